// Round 3
// baseline (677.300 us; speedup 1.0000x reference)
//
#include <hip/hip_runtime.h>

// Stability of stochastic-computing bit streams.
// Per stream n: cnt_t = cumsum(bits), pp = cnt/t*2-1, pe = pp - clip(src,-1,1),
// cts = last t with |pe| > 0.05, stability = 1 - clamp(cts,1,T)/T.
//
// R3: minimal-register / max-occupancy variant. One stream per thread, scalar
// dword loads (256 B/wave, fully coalesced), 2048 blocks = 8 blocks/CU =
// 32 waves/CU. __launch_bounds__(256,8) pins VGPRs <= 64 so spilling is
// impossible (R1/R2's 4-stream x unroll-8 f64 chains plausibly spilled;
// both sat at ~700 us vs the 86 us HBM floor).
//
// Bit-exactness without f32 division: for c in [0,256], t in [1,256], c/t in
// lowest terms has denominator <= 2^8, so it is never an f32 rounding midpoint
// (those need denominators >= 2^24); its distance to any midpoint is >= ~2^-33
// relative, while (double)c * RN64(1/t) carries error <= 2^-52. Hence
//   (float)((double)c * rcp64[t])  ==  (float)c / (float)t   bit-for-bit.
// fmaf(q,2,-1) == RN(2q-1) matches ref's (q*2)-1 since 2q is exact.

#define THR 0.05f

__global__ __launch_bounds__(256, 8) void stability_kernel(
    const float* __restrict__ src,
    const int*   __restrict__ bits,   // [T][n]
    float* __restrict__ out,
    int n, int T)
{
    __shared__ double rcp[256];       // rcp[t-1] = RN64(1/t), wave-uniform reads
    for (int u = threadIdx.x; u < T; u += 256)
        rcp[u] = 1.0 / (double)(u + 1);
    __syncthreads();

    int i = blockIdx.x * 256 + threadIdx.x;
    if (i >= n) return;

    float s = fminf(fmaxf(src[i], -1.0f), 1.0f);

    int c = 0;   // running one-count
    int l = 0;   // last unstable cycle (0 = never)

    const int* p = bits + i;
    #pragma unroll 8
    for (int t = 0; t < T; ++t) {
        int b = *p;
        p += n;
        c += b;
        float q  = (float)((double)c * rcp[t]);  // == (float)c/(float)(t+1), exact
        float pe = fmaf(q, 2.0f, -1.0f) - s;
        if (fabsf(pe) > THR) l = t + 1;
    }

    out[i] = 1.0f - (float)min(max(l, 1), T) / (float)T;
}

extern "C" void kernel_launch(void* const* d_in, const int* in_sizes, int n_in,
                              void* d_out, int out_size, void* d_ws, size_t ws_size,
                              hipStream_t stream) {
    const float* source = (const float*)d_in[0];
    const int*   bits   = (const int*)d_in[1];
    float*       out    = (float*)d_out;

    int n = in_sizes[0];          // 524288 streams
    int T = in_sizes[1] / n;      // 256 cycles

    const int block = 256;
    int grid = (n + block - 1) / block;   // 2048 blocks -> 8 blocks/CU

    stability_kernel<<<grid, block, 0, stream>>>(source, bits, out, n, T);
}

// Round 4
// 648.257 us; speedup vs baseline: 1.0448x; 1.0448x over previous
//
#include <hip/hip_runtime.h>

// Stability of stochastic-computing bit streams.
// Per stream n: cnt_t = cumsum(bits), pp = cnt/t*2-1, pe = pp - clip(src,-1,1),
// cts = last t with |pe| > 0.05, stability = 1 - clamp(cts,1,T)/T.
//
// R4: nontemporal streaming variant. Evidence so far: R1/R2/R3 (radically
// different register/occupancy shapes) all land at ~672-717 us, while the
// rocprof top-5 shows only 340 us harness fills -> our kernel is <341 us and
// the bench window includes ~510-590 us of harness poison/restore. Kernel is
// ~90-165 us vs the 86 us HBM floor (bits = 512 MiB read-once).
// This round: __builtin_nontemporal_load on bits (read-once stream, 2x L3 —
// caching it is pure loss) + dwordx2 loads (2 streams/thread, 512 B/wave).
// If dur is unchanged, the kernel is floor-bound and we stop.
//
// Bit-exactness without f32 division: for c in [0,256], t in [1,256], c/t in
// lowest terms has denominator <= 2^8, so it is never an f32 rounding midpoint
// (those need denominators >= 2^24); distance to any midpoint >= ~2^-33
// relative, while (double)c * RN64(1/t) carries error <= 2^-52. Hence
//   (float)((double)c * rcp64[t])  ==  (float)c / (float)t   bit-for-bit.
// fmaf(q,2,-1) == RN(2q-1) matches ref's (q*2)-1 since 2q is exact.

#define THR 0.05f

__global__ __launch_bounds__(256, 8) void stability_kernel(
    const float2* __restrict__ src2,
    const long long* __restrict__ bits2,   // [T][n2], two bit-streams per qword
    float2* __restrict__ out2,
    int n2, int T)
{
    __shared__ double rcp[256];       // rcp[t-1] = RN64(1/t), wave-uniform reads
    for (int u = threadIdx.x; u < T; u += 256)
        rcp[u] = 1.0 / (double)(u + 1);
    __syncthreads();

    int i = blockIdx.x * 256 + threadIdx.x;
    if (i >= n2) return;

    float2 s = src2[i];
    float s0 = fminf(fmaxf(s.x, -1.0f), 1.0f);
    float s1 = fminf(fmaxf(s.y, -1.0f), 1.0f);

    int c0 = 0, c1 = 0;   // running one-counts
    int l0 = 0, l1 = 0;   // last unstable cycle (0 = never)

    const long long* p = bits2 + i;
    #pragma unroll 8
    for (int t = 0; t < T; ++t) {
        long long v = __builtin_nontemporal_load(p);   // global_load_dwordx2 ... nt
        p += n2;
        c0 += (int)(v & 0xffffffffLL);   // bits[t][2i]   (values are 0/1)
        c1 += (int)(v >> 32);            // bits[t][2i+1]
        double r = rcp[t];
        float q0 = (float)((double)c0 * r);  // == (float)c0/(float)(t+1), exact
        float q1 = (float)((double)c1 * r);
        float pe0 = fmaf(q0, 2.0f, -1.0f) - s0;
        float pe1 = fmaf(q1, 2.0f, -1.0f) - s1;
        if (fabsf(pe0) > THR) l0 = t + 1;
        if (fabsf(pe1) > THR) l1 = t + 1;
    }

    float Tf = (float)T;
    float2 o;
    o.x = 1.0f - (float)min(max(l0, 1), T) / Tf;
    o.y = 1.0f - (float)min(max(l1, 1), T) / Tf;
    out2[i] = o;
}

extern "C" void kernel_launch(void* const* d_in, const int* in_sizes, int n_in,
                              void* d_out, int out_size, void* d_ws, size_t ws_size,
                              hipStream_t stream) {
    const float* source = (const float*)d_in[0];
    const int*   bits   = (const int*)d_in[1];
    float*       out    = (float*)d_out;

    int n  = in_sizes[0];          // 524288 streams
    int T  = in_sizes[1] / n;      // 256 cycles
    int n2 = n / 2;                // 2 streams per thread

    const int block = 256;
    int grid = (n2 + block - 1) / block;   // 1024 blocks -> 4 blocks/CU

    stability_kernel<<<grid, block, 0, stream>>>(
        (const float2*)source, (const long long*)bits, (float2*)out, n2, T);
}